// Round 18
// baseline (63.245 us; speedup 1.0000x reference)
//
#include <hip/hip_runtime.h>
#include <hip/hip_fp16.h>

#define N_NODES 65536
#define N_EDGES 1048576
#define IN_DIM 128
#define OUT_DIM 64
#define NBUCK 1024     // bucket = row >> 6
#define BROWS 64       // rows per bucket
#define EPB 4096       // edges per stage block (16/thread: no VGPR spill — R11 lesson)
#define SLABC 1280     // slab capacity per bucket (mean 1024, +8 sigma)
#define GEMM_BLOCKS (N_NODES / 64)   // 1024
#define STAGE_BLOCKS (N_EDGES / EPB) // 256

typedef __attribute__((ext_vector_type(8))) short short8;
typedef __attribute__((ext_vector_type(4))) float f32x4;
typedef __attribute__((ext_vector_type(2))) float f32x2;
typedef __attribute__((ext_vector_type(2))) unsigned int u32x2;

__device__ __forceinline__ short bf16b(float x) {
    union { float f; unsigned int u; } c; c.f = x;
    unsigned int r = (c.u + 0x7FFFu + ((c.u >> 16) & 1u)) >> 16;   // RNE
    return (short)r;
}

// ---------------- Merged: GEMM (blocks 0..1023) ∥ stage (blocks 1024..1279) --
// GEMM: S = X @ W via bf16 MFMA, no LDS. Wave w owns rows [blk*64 + w*16, +16).
// C/D (m89-verified): col = ct*16 + (lane&15), row = row0 + (lane>>4)*4 + r.
// S stored as TWO CONTIGUOUS DIM-PLANES: S_lo[node][0:32], S_hi[node][32:64]
// (4.2 MB each) so the gather's per-pass working set is contiguous and
// ~L2-sized (R16 lesson: sub-line phasing aliases L2 sets; planes don't).
// Stage: bucket edges by row>>6 into per-bucket uint2 slabs; LDS hist -> one
// global cursor atomic per (block,bucket) -> dense appends. No NT stores
// (R14 lesson). gcur pre-zeroed by memsetAsync.
__global__ __launch_bounds__(256) void gemm_stage_kernel(const float* __restrict__ X,
                                                         const float* __restrict__ W,
                                                         __half* __restrict__ S_lo,
                                                         __half* __restrict__ S_hi,
                                                         const int* __restrict__ erow,
                                                         const int* __restrict__ ecol,
                                                         const float* __restrict__ evals,
                                                         int* __restrict__ gcur,
                                                         uint2* __restrict__ staged) {
    if (blockIdx.x < GEMM_BLOCKS) {
        // ---------------- GEMM part ----------------
        const int wid = threadIdx.x >> 6;
        const int lane = threadIdx.x & 63;
        const int row0 = blockIdx.x * 64 + wid * 16;
        const int lrow = lane & 15;
        const int hi = lane >> 4;

        short8 bfr[4][4];
#pragma unroll
        for (int ct = 0; ct < 4; ++ct) {
            const float* wp = W + (size_t)(hi * 8) * OUT_DIM + ct * 16 + lrow;
#pragma unroll
            for (int kt = 0; kt < 4; ++kt) {
                const float* wk = wp + (size_t)kt * 32 * OUT_DIM;
#pragma unroll
                for (int j = 0; j < 8; ++j)
                    bfr[ct][kt][j] = bf16b(wk[(size_t)j * OUT_DIM]);
            }
        }

        f32x4 acc[4] = {};
#pragma unroll
        for (int kt = 0; kt < 4; ++kt) {
            const float* xp = X + (size_t)(row0 + lrow) * IN_DIM + kt * 32 + hi * 8;
            float4 x0 = *reinterpret_cast<const float4*>(xp);
            float4 x1 = *reinterpret_cast<const float4*>(xp + 4);
            short8 af;
            af[0] = bf16b(x0.x); af[1] = bf16b(x0.y); af[2] = bf16b(x0.z); af[3] = bf16b(x0.w);
            af[4] = bf16b(x1.x); af[5] = bf16b(x1.y); af[6] = bf16b(x1.z); af[7] = bf16b(x1.w);
#pragma unroll
            for (int ct = 0; ct < 4; ++ct)
                acc[ct] = __builtin_amdgcn_mfma_f32_16x16x32_bf16(af, bfr[ct][kt], acc[ct], 0, 0, 0);
        }
#pragma unroll
        for (int ct = 0; ct < 4; ++ct) {
            __half* Sp = (ct < 2) ? S_lo : S_hi;
            const int cip = (ct & 1) * 16 + lrow;     // col within 32-dim plane
#pragma unroll
            for (int r = 0; r < 4; ++r)
                Sp[(size_t)(row0 + hi * 4 + r) * 32 + cip] = __float2half_rn(acc[ct][r]);
        }
    } else {
        // ---------------- Stage part ----------------
        __shared__ int cnt[NBUCK];
        __shared__ int base[NBUCK];
        __shared__ int cnt2[NBUCK];
        const int t = threadIdx.x;
        for (int i = t; i < NBUCK; i += 256) { cnt[i] = 0; cnt2[i] = 0; }
        __syncthreads();

        unsigned int rc[16];
        float v[16];
        const int e0 = (blockIdx.x - GEMM_BLOCKS) * EPB;
#pragma unroll
        for (int i = 0; i < 16; ++i) {
            int e = e0 + i * 256 + t;                 // coalesced
            unsigned int r = (unsigned int)erow[e];
            unsigned int c = (unsigned int)ecol[e];
            rc[i] = (r << 16) | c;
            v[i] = evals[e];
            atomicAdd(&cnt[r >> 6], 1);
        }
        __syncthreads();
        for (int i = t; i < NBUCK; i += 256) {
            int c = cnt[i];
            if (c) base[i] = i * SLABC + atomicAdd(&gcur[i], c);
        }
        __syncthreads();
#pragma unroll
        for (int i = 0; i < 16; ++i) {
            int b = rc[i] >> 22;                      // row >> 6
            int pos = base[b] + atomicAdd(&cnt2[b], 1);
            if (pos < (b + 1) * SLABC)                // overflow guard (deterministic data)
                staged[pos] = make_uint2(rc[i], __float_as_uint(v[i]));
        }
    }
}

__device__ __forceinline__ int wave_incl_scan(int v, int lane) {
#pragma unroll
    for (int d = 1; d < 64; d <<= 1) {
        int t = __shfl_up(v, d, 64);
        if (lane >= d) v += t;
    }
    return v;
}

// ---------------- Fused sort + gather + finalize (dim-plane 2-pass) ----------
// One 512-thread block per 64-row bucket. Phase 1: counting-sort the slab by
// local row into LDS (NT slab loads via u32x2 ext-vector: read-once, keep L2
// for S). Phase 2: TWO dim-passes, pass loop outermost — pass 0 touches only
// the contiguous S_lo plane (one 64 B line per row, 16 lanes x ushort2),
// pass 1 only S_hi; the per-pass S working set (4.2 MB contiguous) is
// ~XCD-L2-sized, converting most S misses from L3-latency to L2-latency.
// 8-wide clamped loop (R15: MLP saturates); consecutive rows per group (R12).
__global__ __launch_bounds__(512) void sort_gather_kernel(const int* __restrict__ gcur,
                                                          const uint2* __restrict__ slab,
                                                          const __half* __restrict__ S_lo,
                                                          const __half* __restrict__ S_hi,
                                                          const float* __restrict__ prior,
                                                          const float* __restrict__ bias,
                                                          float* __restrict__ out) {
    __shared__ uint2 scvp[SLABC];            // 10,240 B sorted entries
    __shared__ int cnt[BROWS];
    __shared__ int excl[BROWS];
    __shared__ int cnt2[BROWS];
    const int t = threadIdx.x;
    const int b = blockIdx.x;
    const int count = min(gcur[b], SLABC);
    const u32x2* ms = reinterpret_cast<const u32x2*>(slab + (size_t)b * SLABC);

    if (t < BROWS) { cnt[t] = 0; cnt2[t] = 0; }
    __syncthreads();

    u32x2 ent[3];                             // ceil(SLABC/512) = 3, static idx
    unsigned int lr[3];
#pragma unroll
    for (int i = 0; i < 3; ++i) {
        int idx = i * 512 + t;
        if (idx < count) {
            ent[i] = __builtin_nontemporal_load(&ms[idx]);
            lr[i] = (ent[i].x >> 16) & (BROWS - 1);
            atomicAdd(&cnt[lr[i]], 1);
        }
    }
    __syncthreads();
    if (t < 64) {                             // wave 0: exclusive scan of 64 counts
        int v = cnt[t];
        int inc = wave_incl_scan(v, t);
        excl[t] = inc - v;
    }
    __syncthreads();
#pragma unroll
    for (int i = 0; i < 3; ++i) {
        int idx = i * 512 + t;
        if (idx < count) {
            int pos = excl[lr[i]] + atomicAdd(&cnt2[lr[i]], 1);
            scvp[pos] = make_uint2(ent[i].x, ent[i].y);
        }
    }
    __syncthreads();

    // ---------------- gather: 2 dim-passes, pass outermost ----------------
    const int g = t >> 4;                     // group 0..31
    const int sub = t & 15;
#pragma unroll
    for (int pass = 0; pass < 2; ++pass) {
        const ushort2* Sp = reinterpret_cast<const ushort2*>(pass ? S_hi : S_lo); // [node][16]
#pragma unroll
        for (int nn = 0; nn < 2; ++nn) {
            const int lrow = g * 2 + nn;      // 0..63 (consecutive: write locality)
            const int start = excl[lrow];
            const int end = start + cnt[lrow];
            float ax = 0.f, ay = 0.f;
            for (int j = start; j < end; j += 8) {
                unsigned int col[8];
                float w[8];
#pragma unroll
                for (int q = 0; q < 8; ++q) {
                    int idx = j + q;
                    bool valid = idx < end;
                    uint2 e = scvp[valid ? idx : start];   // LDS broadcast, clamped
                    col[q] = e.x & 0xFFFFu;
                    w[q] = valid ? __uint_as_float(e.y) : 0.f;
                }
                ushort2 s[8];
#pragma unroll
                for (int q = 0; q < 8; ++q)
                    s[q] = Sp[(size_t)col[q] * 16 + sub];
#pragma unroll
                for (int q = 0; q < 8; ++q) {
                    ax += w[q] * __half2float(__ushort_as_half(s[q].x));
                    ay += w[q] * __half2float(__ushort_as_half(s[q].y));
                }
            }
            const size_t nbase = (size_t)(b * BROWS + lrow) * OUT_DIM + pass * 32 + sub * 2;
            f32x2 p = __builtin_nontemporal_load(reinterpret_cast<const f32x2*>(prior + nbase));
            const float bx = bias[pass * 32 + sub * 2];
            const float by = bias[pass * 32 + sub * 2 + 1];
            f32x2 r;
            r.x = p.x * ax + bx;
            r.y = p.y * ay + by;
            __builtin_nontemporal_store(r, reinterpret_cast<f32x2*>(out + nbase));
        }
    }
}

extern "C" void kernel_launch(void* const* d_in, const int* in_sizes, int n_in,
                              void* d_out, int out_size, void* d_ws, size_t ws_size,
                              hipStream_t stream) {
    const float* X     = (const float*)d_in[0];
    const int*   erow  = (const int*)d_in[1];
    const int*   ecol  = (const int*)d_in[2];
    const float* evals = (const float*)d_in[3];
    const float* prior = (const float*)d_in[4];
    const float* W     = (const float*)d_in[5];
    const float* bias  = (const float*)d_in[6];
    float* out = (float*)d_out;

    // workspace layout (~18.9 MB total)
    char* ws = (char*)d_ws;
    __half* S_lo = (__half*)ws;                            //  4,194,304 B
    __half* S_hi = (__half*)(ws + 4194304);                //  4,194,304 B
    uint2*  slab = (uint2*)(ws + 8388608);                 // 10,485,760 B (1024*1280*8)
    int*    gcur = (int*)(ws + 8388608 + 10485760);        //      4,096 B

    hipMemsetAsync(gcur, 0, NBUCK * sizeof(int), stream);
    gemm_stage_kernel<<<GEMM_BLOCKS + STAGE_BLOCKS, 256, 0, stream>>>(
        X, W, S_lo, S_hi, erow, ecol, evals, gcur, slab);
    sort_gather_kernel<<<NBUCK, 512, 0, stream>>>(gcur, slab, S_lo, S_hi, prior, bias, out);
}

// Round 19
// 55.351 us; speedup vs baseline: 1.1426x; 1.1426x over previous
//
#include <hip/hip_runtime.h>
#include <hip/hip_fp16.h>

#define N_NODES 65536
#define N_EDGES 1048576
#define IN_DIM 128
#define OUT_DIM 64
#define NBUCK 1024     // bucket = row >> 6
#define BROWS 64       // rows per bucket
#define EPB 4096       // edges per stage block (16/thread: no VGPR spill — R11 lesson)
#define SLABC 1280     // slab capacity per bucket (mean 1024, +8 sigma)
#define GEMM_BLOCKS (N_NODES / 64)   // 1024
#define STAGE_BLOCKS (N_EDGES / EPB) // 256

typedef __attribute__((ext_vector_type(8))) short short8;
typedef __attribute__((ext_vector_type(4))) float f32x4;

__device__ __forceinline__ short bf16b(float x) {
    union { float f; unsigned int u; } c; c.f = x;
    unsigned int r = (c.u + 0x7FFFu + ((c.u >> 16) & 1u)) >> 16;   // RNE
    return (short)r;
}

// ---------------- Merged: stage (blocks 0..255) ∥ GEMM (blocks 256..1279) ----
// Stage FIRST in dispatch order: it's the longer pole, so it must start at
// t=0 instead of waiting for gemm blocks to retire (R18 change).
// Stage: bucket edges by row>>6 into per-bucket uint2 slabs (row<<16|col, f32
// val bits). SINGLE LDS-atomic pass: lpos = atomicAdd(&cnt[b],1) is both the
// histogram and the placement rank (halves stage LDS atomics vs R13).
// GEMM: S = X @ W via bf16 MFMA, no LDS. Wave w owns rows [blk*64 + w*16, +16).
// C/D (m89-verified): col = ct*16 + (lane&15), row = row0 + (lane>>4)*4 + r.
// No NT stores anywhere (R14 lesson). gcur pre-zeroed by memsetAsync.
__global__ __launch_bounds__(256) void gemm_stage_kernel(const float* __restrict__ X,
                                                         const float* __restrict__ W,
                                                         __half* __restrict__ S,
                                                         const int* __restrict__ erow,
                                                         const int* __restrict__ ecol,
                                                         const float* __restrict__ evals,
                                                         int* __restrict__ gcur,
                                                         uint2* __restrict__ staged) {
    if (blockIdx.x < STAGE_BLOCKS) {
        // ---------------- Stage part ----------------
        __shared__ int cnt[NBUCK];
        __shared__ int base[NBUCK];
        const int t = threadIdx.x;
        for (int i = t; i < NBUCK; i += 256) cnt[i] = 0;
        __syncthreads();

        unsigned int rc[16];
        float v[16];
        int lpos[16];
        const int e0 = blockIdx.x * EPB;
#pragma unroll
        for (int i = 0; i < 16; ++i) {
            int e = e0 + i * 256 + t;                 // coalesced
            unsigned int r = (unsigned int)erow[e];
            unsigned int c = (unsigned int)ecol[e];
            rc[i] = (r << 16) | c;
            v[i] = evals[e];
            lpos[i] = atomicAdd(&cnt[r >> 6], 1);     // hist AND placement rank
        }
        __syncthreads();
        for (int i = t; i < NBUCK; i += 256) {
            int c = cnt[i];
            if (c) base[i] = i * SLABC + atomicAdd(&gcur[i], c);
        }
        __syncthreads();
#pragma unroll
        for (int i = 0; i < 16; ++i) {
            int b = rc[i] >> 22;                      // row >> 6
            int pos = base[b] + lpos[i];
            if (pos < (b + 1) * SLABC)                // overflow guard (deterministic data)
                staged[pos] = make_uint2(rc[i], __float_as_uint(v[i]));
        }
    } else {
        // ---------------- GEMM part ----------------
        const int gblk = blockIdx.x - STAGE_BLOCKS;
        const int wid = threadIdx.x >> 6;
        const int lane = threadIdx.x & 63;
        const int row0 = gblk * 64 + wid * 16;
        const int lrow = lane & 15;
        const int hi = lane >> 4;

        short8 bfr[4][4];
#pragma unroll
        for (int ct = 0; ct < 4; ++ct) {
            const float* wp = W + (size_t)(hi * 8) * OUT_DIM + ct * 16 + lrow;
#pragma unroll
            for (int kt = 0; kt < 4; ++kt) {
                const float* wk = wp + (size_t)kt * 32 * OUT_DIM;
#pragma unroll
                for (int j = 0; j < 8; ++j)
                    bfr[ct][kt][j] = bf16b(wk[(size_t)j * OUT_DIM]);
            }
        }

        f32x4 acc[4] = {};
#pragma unroll
        for (int kt = 0; kt < 4; ++kt) {
            const float* xp = X + (size_t)(row0 + lrow) * IN_DIM + kt * 32 + hi * 8;
            float4 x0 = *reinterpret_cast<const float4*>(xp);
            float4 x1 = *reinterpret_cast<const float4*>(xp + 4);
            short8 af;
            af[0] = bf16b(x0.x); af[1] = bf16b(x0.y); af[2] = bf16b(x0.z); af[3] = bf16b(x0.w);
            af[4] = bf16b(x1.x); af[5] = bf16b(x1.y); af[6] = bf16b(x1.z); af[7] = bf16b(x1.w);
#pragma unroll
            for (int ct = 0; ct < 4; ++ct)
                acc[ct] = __builtin_amdgcn_mfma_f32_16x16x32_bf16(af, bfr[ct][kt], acc[ct], 0, 0, 0);
        }
#pragma unroll
        for (int ct = 0; ct < 4; ++ct)
#pragma unroll
            for (int r = 0; r < 4; ++r)
                S[(size_t)(row0 + hi * 4 + r) * OUT_DIM + ct * 16 + lrow] =
                    __float2half_rn(acc[ct][r]);
    }
}

__device__ __forceinline__ int wave_incl_scan(int v, int lane) {
#pragma unroll
    for (int d = 1; d < 64; d <<= 1) {
        int t = __shfl_up(v, d, 64);
        if (lane >= d) v += t;
    }
    return v;
}

// ---------------- Fused sort + gather + finalize (R13 structure, unchanged) --
// One 512-thread block per 64-row bucket. Phase 1: counting-sort the bucket's
// slab by local row into LDS. Phase 2: 32 groups of 16 lanes gather 2
// CONSECUTIVE nodes each (R12 lesson: write locality). S rows read as ushort4
// (4 random rows per load instr). Clamped 8-wide loop (R15: MLP saturates at
// 8; R16/R17 col-phase & dim-plane restructurings both regressed — this is
// the empirical random-access floor).
__global__ __launch_bounds__(512) void sort_gather_kernel(const int* __restrict__ gcur,
                                                          const uint2* __restrict__ slab,
                                                          const __half* __restrict__ S,
                                                          const float* __restrict__ prior,
                                                          const float* __restrict__ bias,
                                                          float* __restrict__ out) {
    __shared__ uint2 scvp[SLABC];            // 10,240 B sorted entries
    __shared__ int cnt[BROWS];
    __shared__ int excl[BROWS];
    __shared__ int cnt2[BROWS];
    const int t = threadIdx.x;
    const int b = blockIdx.x;
    const int count = min(gcur[b], SLABC);
    const uint2* ms = slab + (size_t)b * SLABC;

    if (t < BROWS) { cnt[t] = 0; cnt2[t] = 0; }
    __syncthreads();

    uint2 ent[3];                             // ceil(SLABC/512) = 3, static idx
    unsigned int lr[3];
#pragma unroll
    for (int i = 0; i < 3; ++i) {
        int idx = i * 512 + t;
        if (idx < count) {
            ent[i] = ms[idx];
            lr[i] = (ent[i].x >> 16) & (BROWS - 1);
            atomicAdd(&cnt[lr[i]], 1);
        }
    }
    __syncthreads();
    if (t < 64) {                             // wave 0: exclusive scan of 64 counts
        int v = cnt[t];
        int inc = wave_incl_scan(v, t);
        excl[t] = inc - v;
    }
    __syncthreads();
#pragma unroll
    for (int i = 0; i < 3; ++i) {
        int idx = i * 512 + t;
        if (idx < count) {
            int pos = excl[lr[i]] + atomicAdd(&cnt2[lr[i]], 1);
            scvp[pos] = ent[i];
        }
    }
    __syncthreads();

    // ---------------- gather phase ----------------
    const int g = t >> 4;                     // group 0..31
    const int sub = t & 15;
    const ushort4* S4 = reinterpret_cast<const ushort4*>(S);   // 16 ushort4/row
#pragma unroll
    for (int nn = 0; nn < 2; ++nn) {
        const int lrow = g * 2 + nn;          // 0..63 (consecutive: write locality)
        const int start = excl[lrow];
        const int end = start + cnt[lrow];
        float ax = 0.f, ay = 0.f, az = 0.f, aw = 0.f;
        for (int j = start; j < end; j += 8) {
            unsigned int col[8];
            float w[8];
#pragma unroll
            for (int q = 0; q < 8; ++q) {
                int idx = j + q;
                bool valid = idx < end;
                uint2 e = scvp[valid ? idx : start];       // LDS broadcast, clamped
                col[q] = e.x & 0xFFFFu;
                w[q] = valid ? __uint_as_float(e.y) : 0.f;
            }
            ushort4 s[8];
#pragma unroll
            for (int q = 0; q < 8; ++q)
                s[q] = S4[(size_t)col[q] * 16 + sub];
#pragma unroll
            for (int q = 0; q < 8; ++q) {
                ax += w[q] * __half2float(__ushort_as_half(s[q].x));
                ay += w[q] * __half2float(__ushort_as_half(s[q].y));
                az += w[q] * __half2float(__ushort_as_half(s[q].z));
                aw += w[q] * __half2float(__ushort_as_half(s[q].w));
            }
        }
        const size_t nbase = (size_t)(b * BROWS + lrow) * OUT_DIM + sub * 4;
        f32x4 p = __builtin_nontemporal_load(reinterpret_cast<const f32x4*>(prior + nbase));
        float4 bb = *reinterpret_cast<const float4*>(&bias[sub * 4]);
        f32x4 r;
        r.x = p.x * ax + bb.x;
        r.y = p.y * ay + bb.y;
        r.z = p.z * az + bb.z;
        r.w = p.w * aw + bb.w;
        __builtin_nontemporal_store(r, reinterpret_cast<f32x4*>(out + nbase));
    }
}

extern "C" void kernel_launch(void* const* d_in, const int* in_sizes, int n_in,
                              void* d_out, int out_size, void* d_ws, size_t ws_size,
                              hipStream_t stream) {
    const float* X     = (const float*)d_in[0];
    const int*   erow  = (const int*)d_in[1];
    const int*   ecol  = (const int*)d_in[2];
    const float* evals = (const float*)d_in[3];
    const float* prior = (const float*)d_in[4];
    const float* W     = (const float*)d_in[5];
    const float* bias  = (const float*)d_in[6];
    float* out = (float*)d_out;

    // workspace layout (~18.9 MB total)
    char* ws = (char*)d_ws;
    __half* S    = (__half*)ws;                            //  8,388,608 B
    uint2*  slab = (uint2*)(ws + 8388608);                 // 10,485,760 B (1024*1280*8)
    int*    gcur = (int*)(ws + 8388608 + 10485760);        //      4,096 B

    hipMemsetAsync(gcur, 0, NBUCK * sizeof(int), stream);
    gemm_stage_kernel<<<GEMM_BLOCKS + STAGE_BLOCKS, 256, 0, stream>>>(
        X, W, S, erow, ecol, evals, gcur, slab);
    sort_gather_kernel<<<NBUCK, 512, 0, stream>>>(gcur, slab, S, prior, bias, out);
}